// Round 3
// baseline (161.361 us; speedup 1.0000x reference)
//
#include <hip/hip_runtime.h>
#include <stdint.h>

static constexpr int Kdim  = 1024;    // L
static constexpr int Ncols = 512;     // OUT

typedef __attribute__((ext_vector_type(8))) short bf16x8;
typedef __attribute__((ext_vector_type(4))) float f32x4;

__device__ __forceinline__ unsigned short f2bf(float f) {
  unsigned u = __builtin_bit_cast(unsigned, f);
  u += 0x7FFFu + ((u >> 16) & 1u);          // RNE
  return (unsigned short)(u >> 16);
}
__device__ __forceinline__ unsigned f2bf2(float lo, float hi) {
  unsigned ul = __builtin_bit_cast(unsigned, lo);
  unsigned uh = __builtin_bit_cast(unsigned, hi);
  ul += 0x7FFFu + ((ul >> 16) & 1u);
  uh += 0x7FFFu + ((uh >> 16) & 1u);
  return (ul >> 16) | (uh & 0xFFFF0000u);
}

// async global->LDS, 16B per lane; LDS dest = uniform base + lane*16
__device__ __forceinline__ void gl2lds16(const void* g, void* l) {
  __builtin_amdgcn_global_load_lds(
      (const __attribute__((address_space(1))) void*)g,
      (__attribute__((address_space(3))) void*)l, 16, 0, 0);
}

// ---------------------------------------------------------------------------
// Kernel 1 (tiny, ~2us): Wt[n][k] = bf16(0.5*(W_in[k][n]+W_out[k][n])+W_root[k][n])
// ---------------------------------------------------------------------------
__global__ __launch_bounds__(256) void combine_w(
    const float* __restrict__ Win, const float* __restrict__ Wout,
    const float* __restrict__ Wroot, unsigned short* __restrict__ Wt)
{
  __shared__ unsigned short lds[32 * 36];
  const int bid = blockIdx.x;
  const int tk0 = (bid & 31) * 32;
  const int tn0 = (bid >> 5) * 32;
  const int t = threadIdx.x;
  {
    const int k  = t >> 3;
    const int nq = (t & 7) * 4;
    const int gi = (tk0 + k) * Ncols + tn0 + nq;
    const float4 wi = *(const float4*)(Win + gi);
    const float4 wo = *(const float4*)(Wout + gi);
    const float4 wr = *(const float4*)(Wroot + gi);
    lds[(nq + 0) * 36 + k] = f2bf(0.5f * (wi.x + wo.x) + wr.x);
    lds[(nq + 1) * 36 + k] = f2bf(0.5f * (wi.y + wo.y) + wr.y);
    lds[(nq + 2) * 36 + k] = f2bf(0.5f * (wi.z + wo.z) + wr.z);
    lds[(nq + 3) * 36 + k] = f2bf(0.5f * (wi.w + wo.w) + wr.w);
  }
  __syncthreads();
  {
    const int n  = t >> 3;
    const int k8 = (t & 7) * 4;
    const ushort4 v = *(const ushort4*)&lds[n * 36 + k8];
    *(ushort4*)(Wt + (size_t)(tn0 + n) * Kdim + tk0 + k8) = v;
  }
}

// ---------------------------------------------------------------------------
// Kernel 2: Y = fp32 X @ Wt^T + bias, fused fp32->bf16 conversion in staging.
// 128x128 tile, BK=32, 4 waves 2x2, wave-tile 64x64 (4x4 mfma 16x16x32 bf16).
// LDS double-buffered (2 x (8+8) KB), ONE barrier per iter. Pipeline order per
// iter: barrier -> issue B DMA(it+1) + A global loads(it+1) -> frag reads +
// MFMA on buf[p] -> cvt + ds_write A(it+1) into buf[q]. The barrier's vmcnt(0)
// drain only hits B DMA issued a full MFMA burst earlier (L2-resident Wt);
// A's global latency hides under the MFMA burst (cvt is its first use).
// XOR 16B-slot swizzle (slot = chunk ^ ((row>>1)&3)) keeps global_load_lds
// contiguity AND spreads frag ds_read_b128 across banks.
// ---------------------------------------------------------------------------
__global__ __launch_bounds__(256, 2) void gemm_fused2(
    const float* __restrict__ X, const unsigned short* __restrict__ Wt,
    const float* __restrict__ b_in, const float* __restrict__ b_out,
    const float* __restrict__ b_root, float* __restrict__ Y)
{
  __shared__ __attribute__((aligned(16))) short As[2 * 4096];  // 2 x 128x32 bf16
  __shared__ __attribute__((aligned(16))) short Bs[2 * 4096];

  const int bid = blockIdx.x;
  const int m0 = (bid & 127) * 128;
  const int n0 = (bid >> 7) * 128;

  const int t    = threadIdx.x;
  const int lane = t & 63;
  const int w    = t >> 6;
  const int wm   = w >> 1;
  const int wn   = w & 1;
  const int quad = lane >> 4;
  const int lm   = lane & 15;

  // --- A staging (register cvt -> ds_write): thread t handles row sr, 16 K
  const int sr = t >> 1;
  const int sh = t & 1;
  const float* xp = X + (size_t)(m0 + sr) * Kdim + sh * 16;
  const int sw  = (sr >> 1) & 3;
  const int aw0 = sr * 32 + (((2 * sh) ^ sw) * 8);      // chunk 2sh
  const int aw1 = sr * 32 + (((2 * sh + 1) ^ sw) * 8);  // chunk 2sh+1

  // --- B staging (global_load_lds): wave w covers rows w*32..+32
  const int srb = lane >> 2;
  const int ss  = lane & 3;
  const int sc  = ss ^ ((srb >> 1) & 3);
  const unsigned short* gB = Wt + (size_t)(n0 + w * 32 + srb) * Kdim + sc * 8;
  const int rowK = 16 * Kdim;
  const int lb0 = w * 1024;
  const int lb1 = w * 1024 + 512;

  // --- fragment offsets (shorts)
  const int slot = quad ^ ((lm >> 1) & 3);
  const int aoff = (wm * 64 + lm) * 32 + slot * 8;
  const int boff = (wn * 64 + lm) * 32 + slot * 8;

  f32x4 acc[4][4] = {};

  // --- prologue: stage K-slice 0 into buffer 0
  gl2lds16(gB,        &Bs[lb0]);
  gl2lds16(gB + rowK, &Bs[lb1]);
  {
    const float4 a0 = *(const float4*)(xp + 0);
    const float4 a1 = *(const float4*)(xp + 4);
    const float4 a2 = *(const float4*)(xp + 8);
    const float4 a3 = *(const float4*)(xp + 12);
    uint4 p0, p1;
    p0.x = f2bf2(a0.x, a0.y); p0.y = f2bf2(a0.z, a0.w);
    p0.z = f2bf2(a1.x, a1.y); p0.w = f2bf2(a1.z, a1.w);
    p1.x = f2bf2(a2.x, a2.y); p1.y = f2bf2(a2.z, a2.w);
    p1.z = f2bf2(a3.x, a3.y); p1.w = f2bf2(a3.z, a3.w);
    *(uint4*)&As[aw0] = p0;
    *(uint4*)&As[aw1] = p1;
  }

  #pragma unroll 1
  for (int it = 0; it < 32; ++it) {
    const int p = (it & 1) * 4096;
    const int q = p ^ 4096;
    __syncthreads();   // buf[p] staged (prev iter's ds_writes + B DMA drained)

    // issue next-slice loads immediately after the barrier
    const int nx = (it < 31 ? it + 1 : 31) * 32;   // clamp: it=31 re-reads, unused
    gl2lds16(gB + nx,        &Bs[q + lb0]);
    gl2lds16(gB + nx + rowK, &Bs[q + lb1]);
    const float4 a0 = *(const float4*)(xp + nx + 0);
    const float4 a1 = *(const float4*)(xp + nx + 4);
    const float4 a2 = *(const float4*)(xp + nx + 8);
    const float4 a3 = *(const float4*)(xp + nx + 12);

    // compute on buf[p]
    bf16x8 af[4], bfr[4];
    #pragma unroll
    for (int i = 0; i < 4; ++i) af[i]  = *(const bf16x8*)&As[p + aoff + i * 512];
    #pragma unroll
    for (int j = 0; j < 4; ++j) bfr[j] = *(const bf16x8*)&Bs[p + boff + j * 512];
    #pragma unroll
    for (int i = 0; i < 4; ++i)
      #pragma unroll
      for (int j = 0; j < 4; ++j)
        acc[i][j] = __builtin_amdgcn_mfma_f32_16x16x32_bf16(af[i], bfr[j], acc[i][j], 0, 0, 0);

    // stage next A into buf[q] (first use of a0..a3 -> vmcnt wait lands here,
    // after the MFMA burst)
    uint4 p0, p1;
    p0.x = f2bf2(a0.x, a0.y); p0.y = f2bf2(a0.z, a0.w);
    p0.z = f2bf2(a1.x, a1.y); p0.w = f2bf2(a1.z, a1.w);
    p1.x = f2bf2(a2.x, a2.y); p1.y = f2bf2(a2.z, a2.w);
    p1.z = f2bf2(a3.x, a3.y); p1.w = f2bf2(a3.z, a3.w);
    *(uint4*)&As[q + aw0] = p0;
    *(uint4*)&As[q + aw1] = p1;
  }

  // epilogue: D[row=(lane>>4)*4+reg][col=lane&15] per 16x16 tile; bias fused
  #pragma unroll
  for (int j = 0; j < 4; ++j) {
    const int gc = n0 + wn * 64 + j * 16 + lm;
    const float bias = 0.5f * (b_in[gc] + b_out[gc]) + b_root[gc];
    #pragma unroll
    for (int i = 0; i < 4; ++i) {
      const int gr = m0 + wm * 64 + i * 16 + quad * 4;
      float* yp = Y + (size_t)gr * Ncols + gc;
      #pragma unroll
      for (int r = 0; r < 4; ++r)
        yp[(size_t)r * Ncols] = acc[i][j][r] + bias;
    }
  }
}

// ---------------------------------------------------------------------------
extern "C" void kernel_launch(void* const* d_in, const int* in_sizes, int n_in,
                              void* d_out, int out_size, void* d_ws, size_t ws_size,
                              hipStream_t stream)
{
  const float* x      = (const float*)d_in[0];
  // d_in[1] = At : dead input (ChebConv K=1 -> no neighbor aggregation)
  const float* W_in   = (const float*)d_in[2];
  const float* b_in   = (const float*)d_in[3];
  const float* W_out  = (const float*)d_in[4];
  const float* b_out  = (const float*)d_in[5];
  const float* W_root = (const float*)d_in[6];
  const float* b_root = (const float*)d_in[7];
  float* y = (float*)d_out;

  unsigned short* Wt = (unsigned short*)d_ws;   // 512*1024 bf16 = 1 MiB

  combine_w <<<dim3(512), dim3(256), 0, stream>>>(W_in, W_out, W_root, Wt);
  gemm_fused2<<<dim3(512), dim3(256), 0, stream>>>(x, Wt, b_in, b_out, b_root, y);
}

// Round 4
// 160.298 us; speedup vs baseline: 1.0066x; 1.0066x over previous
//
#include <hip/hip_runtime.h>
#include <stdint.h>

static constexpr int Kdim  = 1024;    // L
static constexpr int Ncols = 512;     // OUT

typedef __attribute__((ext_vector_type(8))) short bf16x8;
typedef __attribute__((ext_vector_type(4))) float f32x4;

union pk8 { uint4 u; bf16x8 h; };

__device__ __forceinline__ unsigned short f2bf(float f) {
  unsigned u = __builtin_bit_cast(unsigned, f);
  u += 0x7FFFu + ((u >> 16) & 1u);          // RNE
  return (unsigned short)(u >> 16);
}
__device__ __forceinline__ unsigned f2bf2(float lo, float hi) {
  unsigned ul = __builtin_bit_cast(unsigned, lo);
  unsigned uh = __builtin_bit_cast(unsigned, hi);
  ul += 0x7FFFu + ((ul >> 16) & 1u);
  uh += 0x7FFFu + ((uh >> 16) & 1u);
  return (ul >> 16) | (uh & 0xFFFF0000u);
}

// async global->LDS, 16B per lane; LDS dest = wave-uniform base + lane*16
__device__ __forceinline__ void gl2lds16(const void* g, void* l) {
  __builtin_amdgcn_global_load_lds(
      (const __attribute__((address_space(1))) void*)g,
      (__attribute__((address_space(3))) void*)l, 16, 0, 0);
}

// ---------------------------------------------------------------------------
// Kernel 1 (tiny): Wt[n][k] = bf16(0.5*(W_in[k][n]+W_out[k][n])+W_root[k][n])
// ---------------------------------------------------------------------------
__global__ __launch_bounds__(256) void combine_w(
    const float* __restrict__ Win, const float* __restrict__ Wout,
    const float* __restrict__ Wroot, unsigned short* __restrict__ Wt)
{
  __shared__ unsigned short lds[32 * 36];
  const int bid = blockIdx.x;
  const int tk0 = (bid & 31) * 32;
  const int tn0 = (bid >> 5) * 32;
  const int t = threadIdx.x;
  {
    const int k  = t >> 3;
    const int nq = (t & 7) * 4;
    const int gi = (tk0 + k) * Ncols + tn0 + nq;
    const float4 wi = *(const float4*)(Win + gi);
    const float4 wo = *(const float4*)(Wout + gi);
    const float4 wr = *(const float4*)(Wroot + gi);
    lds[(nq + 0) * 36 + k] = f2bf(0.5f * (wi.x + wo.x) + wr.x);
    lds[(nq + 1) * 36 + k] = f2bf(0.5f * (wi.y + wo.y) + wr.y);
    lds[(nq + 2) * 36 + k] = f2bf(0.5f * (wi.z + wo.z) + wr.z);
    lds[(nq + 3) * 36 + k] = f2bf(0.5f * (wi.w + wo.w) + wr.w);
  }
  __syncthreads();
  {
    const int n  = t >> 3;
    const int k8 = (t & 7) * 4;
    const ushort4 v = *(const ushort4*)&lds[n * 36 + k8];
    *(ushort4*)(Wt + (size_t)(tn0 + n) * Kdim + tk0 + k8) = v;
  }
}

// ---------------------------------------------------------------------------
// Kernel 2: Y = X(fp32) @ Wt^T + bias.
// Tile 64x128 (MxN), BK=32, grid 1024 = 4 blocks/CU (16 waves/CU), 4 waves in
// 2x2, wave-tile 32x64 (2x4 mfma_f32_16x16x32_bf16). ALL staging via
// global_load_lds: A staged as RAW FP32 (16 KB/slice... 8 KB? 64x32x4B = 8 KB),
// converted to bf16 in registers between ds_read and MFMA. B staged bf16.
// LDS double-buffered (2*(8+8) KB = 32 KB), ONE barrier/iter. With 4
// independent blocks per CU the per-iter vmcnt(0)+barrier drains overlap
// across blocks instead of serializing one convoy.
// XOR slot swizzles: A (128B fp32 rows, 8 slots): slot = chunk ^ (row&7);
// B (64B bf16 rows, 4 slots): slot = chunk ^ ((row ^ row>>2)&3) -- the row>>2
// term breaks the stride-64B phase collision (rows r and r+4 same bank).
// ---------------------------------------------------------------------------
__global__ __launch_bounds__(256, 4) void gemm_fused3(
    const float* __restrict__ X, const unsigned short* __restrict__ Wt,
    const float* __restrict__ b_in, const float* __restrict__ b_out,
    const float* __restrict__ b_root, float* __restrict__ Y)
{
  __shared__ __attribute__((aligned(16))) float As[2][64 * 32];   // fp32, 2x8 KB
  __shared__ __attribute__((aligned(16))) short Bs[2][128 * 32];  // bf16, 2x8 KB

  const int bid = blockIdx.x;
  const int m0 = (bid & 255) * 64;    // 256 m-tiles fast: sharers bid+256k same XCD
  const int n0 = (bid >> 8) * 128;    // 4 n-tiles

  const int t    = threadIdx.x;
  const int lane = t & 63;
  const int w    = t >> 6;
  const int wm   = w >> 1;
  const int wn   = w & 1;
  const int quad = lane >> 4;
  const int lm   = lane & 15;

  // --- A DMA: 2 insts/wave, each 8 fp32-rows (128 B/row). lane -> row ra,
  //     slot sa; fetch global chunk ca = sa ^ (ra&7) into slot sa.
  const int ra = lane >> 3;                 // 0..7
  const int sa = lane & 7;
  const int ca = sa ^ ra;
  const float* gA0 = X + (size_t)(m0 + w * 16 + ra) * Kdim + ca * 4;
  const float* gA1 = gA0 + (size_t)8 * Kdim;
  const int lA0 = (w * 16) * 32;            // float offset of dest row-group
  const int lA1 = (w * 16 + 8) * 32;

  // --- B DMA: 2 insts/wave, each 16 bf16-rows (64 B/row).
  const int rb = lane >> 2;                 // 0..15
  const int sb = lane & 3;
  const int cb = sb ^ ((rb ^ (rb >> 2)) & 3);
  const unsigned short* gB0 = Wt + (size_t)(n0 + w * 32 + rb) * Kdim + cb * 8;
  const unsigned short* gB1 = gB0 + (size_t)16 * Kdim;
  const int lB0 = (w * 32) * 32;            // short offset
  const int lB1 = (w * 32 + 16) * 32;

  // --- fragment offsets
  const int sA0 = (2 * quad) ^ (lm & 7);    // fp32 16B-slot of k=quad*8..+3
  const int sA1 = sA0 ^ 1;                  // k=quad*8+4..+7
  const int aoff = (wm * 32 + lm) * 32;     // + i*512 ; + slot*4 floats
  const int swzB = quad ^ ((lm ^ (lm >> 2)) & 3);
  const int boff = (wn * 64 + lm) * 32 + swzB * 8;   // + j*512 shorts

  f32x4 acc[2][4] = {};

  // --- prologue: slice 0 -> buf 0
  gl2lds16(gA0, &As[0][lA0]);
  gl2lds16(gA1, &As[0][lA1]);
  gl2lds16(gB0, &Bs[0][lB0]);
  gl2lds16(gB1, &Bs[0][lB1]);

  #pragma unroll 1
  for (int it = 0; it < 32; ++it) {
    const int p = it & 1;
    const int q = p ^ 1;
    __syncthreads();   // drains this wave's DMA (vmcnt0) -> buf[p] ready

    const int nx = (it < 31 ? it + 1 : 31) * 32;  // clamp: last iter re-reads
    gl2lds16(gA0 + nx, &As[q][lA0]);
    gl2lds16(gA1 + nx, &As[q][lA1]);
    gl2lds16(gB0 + nx, &Bs[q][lB0]);
    gl2lds16(gB1 + nx, &Bs[q][lB1]);

    bf16x8 bfr[4];
    #pragma unroll
    for (int j = 0; j < 4; ++j)
      bfr[j] = *(const bf16x8*)&Bs[p][boff + j * 512];

    bf16x8 af[2];
    #pragma unroll
    for (int i = 0; i < 2; ++i) {
      const f32x4 lo = *(const f32x4*)&As[p][aoff + i * 512 + sA0 * 4];
      const f32x4 hi = *(const f32x4*)&As[p][aoff + i * 512 + sA1 * 4];
      pk8 pk;
      pk.u.x = f2bf2(lo.x, lo.y);
      pk.u.y = f2bf2(lo.z, lo.w);
      pk.u.z = f2bf2(hi.x, hi.y);
      pk.u.w = f2bf2(hi.z, hi.w);
      af[i] = pk.h;
    }

    #pragma unroll
    for (int i = 0; i < 2; ++i)
      #pragma unroll
      for (int j = 0; j < 4; ++j)
        acc[i][j] = __builtin_amdgcn_mfma_f32_16x16x32_bf16(af[i], bfr[j], acc[i][j], 0, 0, 0);
  }

  // epilogue: D[row=(lane>>4)*4+reg][col=lane&15] per 16x16 tile; bias fused
  #pragma unroll
  for (int j = 0; j < 4; ++j) {
    const int gc = n0 + wn * 64 + j * 16 + lm;
    const float bias = 0.5f * (b_in[gc] + b_out[gc]) + b_root[gc];
    #pragma unroll
    for (int i = 0; i < 2; ++i) {
      const int gr = m0 + wm * 32 + i * 16 + quad * 4;
      float* yp = Y + (size_t)gr * Ncols + gc;
      #pragma unroll
      for (int r = 0; r < 4; ++r)
        yp[(size_t)r * Ncols] = acc[i][j][r] + bias;
    }
  }
}

// ---------------------------------------------------------------------------
extern "C" void kernel_launch(void* const* d_in, const int* in_sizes, int n_in,
                              void* d_out, int out_size, void* d_ws, size_t ws_size,
                              hipStream_t stream)
{
  const float* x      = (const float*)d_in[0];
  // d_in[1] = At : dead input (ChebConv K=1 -> no neighbor aggregation)
  const float* W_in   = (const float*)d_in[2];
  const float* b_in   = (const float*)d_in[3];
  const float* W_out  = (const float*)d_in[4];
  const float* b_out  = (const float*)d_in[5];
  const float* W_root = (const float*)d_in[6];
  const float* b_root = (const float*)d_in[7];
  float* y = (float*)d_out;

  unsigned short* Wt = (unsigned short*)d_ws;   // 512*1024 bf16 = 1 MiB

  combine_w <<<dim3(512),  dim3(256), 0, stream>>>(W_in, W_out, W_root, Wt);
  gemm_fused3<<<dim3(1024), dim3(256), 0, stream>>>(x, Wt, b_in, b_out, b_root, y);
}